// Round 15
// baseline (215.003 us; speedup 1.0000x reference)
//
#include <hip/hip_runtime.h>
#include <hip/hip_bf16.h>

typedef _Float16 f16;
typedef _Float16 f16x4 __attribute__((ext_vector_type(4)));
typedef _Float16 f16x8 __attribute__((ext_vector_type(8)));
typedef float f32x4 __attribute__((ext_vector_type(4)));
typedef float f32x16 __attribute__((ext_vector_type(16)));

constexpr int BATCH = 4, C = 512, CQ = 128, N = 4096;
constexpr int FKD = 256; // f(128) + k(128) channels (conceptual; stored split below)

// workspace layout (bytes)
constexpr size_t WS_XT   = 0;                                      // f16 [B][N][C]        16 MB
constexpr size_t WS_FT   = WS_XT   + (size_t)BATCH * N * C * 2;    // f16 [B][N][128]       4 MB
constexpr size_t WS_KT   = WS_FT   + (size_t)BATCH * N * CQ * 2;   // f16 [B][N/4][4][128]  4 MB (tiled K)
constexpr size_t WS_V    = WS_KT   + (size_t)BATCH * N * CQ * 2;   // f16 [B][C/16][N/8][16][8] 16 MB (tiled V)
constexpr size_t WS_WCAT = WS_V    + (size_t)BATCH * C * N * 2;    // f16 [256][512]
constexpr size_t WS_WL   = WS_WCAT + (size_t)FKD * C * 2;          // f16 [512][512]
constexpr size_t WS_BC   = WS_WL   + (size_t)C * C * 2;            // f32 [256]

#define AS1(p) ((const __attribute__((address_space(1))) void*)(p))
#define AS3(p) ((__attribute__((address_space(3))) void*)(p))

// ---------------------------------------------------------------- weights->fp16
__global__ void prep_weights(const float* __restrict__ Wf_w, const float* __restrict__ Wf_b,
                             const float* __restrict__ Wh_w, const float* __restrict__ Wh_b,
                             const float* __restrict__ Wl_w,
                             f16* __restrict__ wcat, f16* __restrict__ wl, float* __restrict__ bcat) {
    int i = blockIdx.x * 256 + threadIdx.x;                 // grid covers C*C
    if (i < FKD * C) {
        int o = i >> 9, c = i & 511;
        float v = (o < CQ) ? Wf_w[o * C + c] : Wh_w[(o - CQ) * C + c];
        wcat[i] = (f16)v;
    }
    if (i < C * C) wl[i] = (f16)Wl_w[i];
    if (i < FKD) bcat[i] = (i < CQ) ? Wf_b[i] : Wh_b[i - CQ];
}

// ---------------------------------------------------------------- x (B,C,N) f32 -> xT (B,N,C) f16
__global__ void transpose_x(const float* __restrict__ x, f16* __restrict__ xt) {
    __shared__ float tile[64][65];
    int gid = blockIdx.x;
    int b = gid >> 9, rem = gid & 511;
    int c0 = (rem >> 6) * 64, n0 = (rem & 63) * 64;
    int t = threadIdx.x;
    int tn = t & 63, tg = t >> 6;
    const float* xp = x + (size_t)b * C * N + (size_t)c0 * N + n0;
#pragma unroll
    for (int r = 0; r < 16; ++r) {
        int cl = tg + r * 4;
        tile[cl][tn] = xp[(size_t)cl * N + tn];
    }
    __syncthreads();
    f16* xo = xt + (size_t)b * N * C + (size_t)n0 * C + c0;
#pragma unroll
    for (int r = 0; r < 16; ++r) {
        int nl = tg + r * 4;
        xo[(size_t)nl * C + tn] = (f16)tile[tn][nl];
    }
}

// ---------------------------------------------------------------- FK projection (64n x 64o per wave)
__global__ void __launch_bounds__(256) proj_fk(const f16* __restrict__ xt, const f16* __restrict__ wcat,
                                               const float* __restrict__ bcat,
                                               f16* __restrict__ ft, f16* __restrict__ kt) {
    int wid = blockIdx.x * 4 + (threadIdx.x >> 6);   // 1024 waves: b(2) nt(6) ot(2)
    int lane = threadIdx.x & 63;
    int li = lane & 15, lg = lane >> 4;
    int b  = wid >> 8;
    int nt = (wid >> 2) & 63;
    int ot = wid & 3;
    int n0 = nt * 64, o0 = ot * 64;
    const f16* ap = xt + (size_t)(b * N + n0 + li) * C + lg * 8;
    const f16* bp = wcat + (size_t)(o0 + li) * C + lg * 8;
    f32x4 acc[4][4] = {};
    for (int ks = 0; ks < 16; ++ks) {
        f16x8 a4[4], b4[4];
#pragma unroll
        for (int t = 0; t < 4; ++t) a4[t] = *(const f16x8*)(ap + (size_t)(t * 16) * C + ks * 32);
#pragma unroll
        for (int t = 0; t < 4; ++t) b4[t] = *(const f16x8*)(bp + (size_t)(t * 16) * C + ks * 32);
#pragma unroll
        for (int tA = 0; tA < 4; ++tA)
#pragma unroll
            for (int tB = 0; tB < 4; ++tB)
                acc[tA][tB] = __builtin_amdgcn_mfma_f32_16x16x32_f16(a4[tA], b4[tB], acc[tA][tB], 0, 0, 0);
    }
#pragma unroll
    for (int tB = 0; tB < 4; ++tB) {
        int o = o0 + tB * 16 + li;
        float bias = bcat[o];
        if (o < CQ) {
#pragma unroll
            for (int tA = 0; tA < 4; ++tA)
#pragma unroll
                for (int r = 0; r < 4; ++r) {
                    int n = n0 + tA * 16 + lg * 4 + r;
                    ft[((size_t)(b * N + n)) * CQ + o] = (f16)(acc[tA][tB][r] + bias);
                }
        } else {
            int ck = o - CQ;
#pragma unroll
            for (int tA = 0; tA < 4; ++tA)
#pragma unroll
                for (int r = 0; r < 4; ++r) {
                    int n = n0 + tA * 16 + lg * 4 + r;
                    kt[(((size_t)b * (N >> 2) + (n >> 2)) * 4 + (n & 3)) * 128 + ck] = (f16)(acc[tA][tB][r] + bias);
                }
        }
    }
}

// ---------------------------------------------------------------- V projection (64c x 64n per wave)
// output tiled: v[b][cp][jb][cl][jl]: cp=c>>4, cl=c&15, jb=n>>3, jl=n&7
__global__ void __launch_bounds__(256) proj_v(const f16* __restrict__ xt, const f16* __restrict__ wl,
                                              const float* __restrict__ wlb, f16* __restrict__ v) {
    int wid = blockIdx.x * 4 + (threadIdx.x >> 6);   // 2048 waves: b(2) ct(3) nt(6)
    int lane = threadIdx.x & 63;
    int li = lane & 15, lg = lane >> 4;
    int b  = wid >> 9;
    int ct = (wid >> 6) & 7;
    int nt = wid & 63;
    int c0 = ct * 64, n0 = nt * 64;
    const f16* ap = wl + (size_t)(c0 + li) * C + lg * 8;
    const f16* bp = xt + (size_t)(b * N + n0 + li) * C + lg * 8;
    f32x4 acc[4][4] = {};
    for (int ks = 0; ks < 16; ++ks) {
        f16x8 a4[4], b4[4];
#pragma unroll
        for (int t = 0; t < 4; ++t) a4[t] = *(const f16x8*)(ap + (size_t)(t * 16) * C + ks * 32);
#pragma unroll
        for (int t = 0; t < 4; ++t) b4[t] = *(const f16x8*)(bp + (size_t)(t * 16) * C + ks * 32);
#pragma unroll
        for (int tA = 0; tA < 4; ++tA)
#pragma unroll
            for (int tB = 0; tB < 4; ++tB)
                acc[tA][tB] = __builtin_amdgcn_mfma_f32_16x16x32_f16(a4[tA], b4[tB], acc[tA][tB], 0, 0, 0);
    }
#pragma unroll
    for (int tA = 0; tA < 4; ++tA)
#pragma unroll
        for (int r = 0; r < 4; ++r) {
            int c = c0 + tA * 16 + lg * 4 + r;
            float bias = wlb[c];
            const size_t cpb = ((size_t)b * 32 + (c >> 4)) * 512;
            const int cl = c & 15;
#pragma unroll
            for (int tB = 0; tB < 4; ++tB) {
                int n = n0 + tB * 16 + li;
                v[(cpb + (n >> 3)) * 128 + cl * 8 + (n & 7)] = (f16)(acc[tA][tB][r] + bias);
            }
        }
}

// ---------------------------------------------------------------- flash attention + residual (v15)
// = v14 structure (16 waves, 64q, KVBLK=256, de-dup'd V, 32x32 MFMA, gld_lds kbuf,
// 2 barriers/256j, 4 waves/SIMD) with the register budget set DIRECTLY:
// amdgpu_waves_per_eu(4,4) -> 512/4 = 128 unified regs/wave (state needs ~112).
// R14 proved the occupancy (43%) but launch_bounds gave a 64-reg budget -> spill
// storm (FETCH 39->133 MB). This pins the budget; body unchanged.
__global__ void __launch_bounds__(1024)
__attribute__((amdgpu_waves_per_eu(4, 4)))
attn(const f16* __restrict__ ft, const f16* __restrict__ kt,
     const f16* __restrict__ v,
     const float* __restrict__ x, const float* __restrict__ alphap,
     float* __restrict__ out) {
    __shared__ __align__(16) f16 kbuf[256 * 128];      // 64 KB, single buffer
    __shared__ __align__(16) f16 pbuf[64 * 256];       // 32 KB shared P
    __shared__ float smax[8][2][32];
    __shared__ float ssum[8][2][32];

    const int tid  = threadIdx.x;
    const int wv   = tid >> 6;                    // 0..15
    const int lane = tid & 63;
    const int li = lane & 15, lg = lane >> 4;     // staging decode
    const int l31 = lane & 31, lh = lane >> 5;    // 32x32 decode
    const int sw = l31 & 7;                       // row-XOR swizzle key
    const int wj = wv & 7;                        // QK j-slice
    const int wi = wv >> 3;                       // QK i-half
    // XCD-pinning: under blk%8 round-robin, each XCD sees a single batch
    const int v0 = blockIdx.x;
    const int b  = (v0 & 7) >> 1;
    const int it = ((v0 & 1) << 5) | (v0 >> 3);
    const int i0 = it * 64;

    // F fragments (B operand of swapped QK): col=i (own i-half), k=ks*16+lh*8+e
    f16x8 fb[8];
    {
        const f16* fp = ft + (size_t)(b * N + i0 + wi * 32 + l31) * CQ + lh * 8;
#pragma unroll
        for (int ks = 0; ks < 8; ++ks) fb[ks] = *(const f16x8*)(fp + ks * 16);
    }

    // K staging via global_load_lds from tiled kt: wave stages rows [wv*16,+16),
    // 4 instrs x 1KB. LDS dest linear (lane -> row lg, granule li); global source
    // granule inverse-swizzled li ^ (row&7), row&7 = (k*4+lg)&7.
    const f16* ktb = kt + (size_t)b * N * 128;
    auto STAGE = [&](int tile) {
#pragma unroll
        for (int k = 0; k < 4; ++k) {
            const f16* gsrc = ktb + (((size_t)(tile * 64 + wv * 4 + k)) * 4 + lg) * 128
                                  + ((li ^ ((k * 4 + lg) & 7)) * 8);
            __builtin_amdgcn_global_load_lds(AS1(gsrc), AS3(&kbuf[(wv * 16 + k * 4) * 128]), 16, 0, 0);
        }
    };

    STAGE(0);
    // tiled V per-lane base: c = wv*32 + l31 -> cp = wv*2 + (l31>>4); jb = lh + ...
    const f16* vL = v + (((size_t)b * 32 + wv * 2 + (l31 >> 4)) * 512 + lh) * 128 + (l31 & 15) * 8;
    const int prow = wi * 32 + l31;               // pbuf row this wave writes (query)
    f32x16 oacc[2] = {};                          // [i-half], cols i = it*32+l31, rows c
    float ms[2] = {-1e30f, -1e30f}, ls[2] = {0.f, 0.f};
    __syncthreads();                              // tile 0 staged

    for (int t = 0; t < 16; ++t) {
        // (a) QK: S^T tile (32j x 32i) = mfma(A=K, B=F), 8 k-steps
        f32x16 s = {};
        __builtin_amdgcn_s_setprio(1);
#pragma unroll
        for (int ks = 0; ks < 8; ++ks) {
            f16x8 kf = *(const f16x8*)(&kbuf[(wj * 32 + l31) * 128 + (((ks * 2 + lh) ^ sw) * 8)]);
            s = __builtin_amdgcn_mfma_f32_32x32x16_f16(kf, fb[ks], s, 0, 0, 0);
        }
        __builtin_amdgcn_s_setprio(0);
        // (b) wave-local max for own query (16 values + cross-half shfl); publish
        float tm = s[0];
#pragma unroll
        for (int r = 1; r < 16; ++r) tm = fmaxf(tm, s[r]);
        tm = fmaxf(tm, __shfl_xor(tm, 32));
        if (lane < 32) smax[wj][wi][l31] = tm;
        __syncthreads();   // barA: kbuf reads done, smax visible
        // (c) stage K(t+1) (drains at barB; read next iter)
        if (t < 15) STAGE(t + 1);
        // (d) global max over 8 j-slices + T13 deferred rescale (both halves)
#pragma unroll
        for (int h = 0; h < 2; ++h) {
            float gm = smax[0][h][l31];
#pragma unroll
            for (int w = 1; w < 8; ++w) gm = fmaxf(gm, smax[w][h][l31]);
            if (!__all(gm <= ms[h] + 8.0f)) {
                float mn = fmaxf(ms[h], gm), sc = __expf(ms[h] - mn);
                ms[h] = mn; ls[h] *= sc;
                oacc[h] *= sc;
            }
        }
        // (e) exp + P write (own S-tile; j = wj*32 + q*8 + lh*4 + r) + partial sum
        float psum = 0.f;
#pragma unroll
        for (int q = 0; q < 4; ++q) {
            f16x4 pk;
#pragma unroll
            for (int r = 0; r < 4; ++r) { float p = __expf(s[q * 4 + r] - ms[wi]); psum += p; pk[r] = (f16)p; }
            const int g = (wj * 4 + q) ^ sw;
            *(f16x4*)(&pbuf[prow * 256 + g * 8 + lh * 4]) = pk;
        }
        psum += __shfl_xor(psum, 32);
        if (lane < 32) ssum[wj][wi][l31] = psum;
        // V prefetch js=0,1 (latency hides under barB)
        f16x8 vaA, vaB;
        vaA = *(const f16x8*)(vL + ((size_t)(t * 32)) * 128);
        vaB = *(const f16x8*)(vL + ((size_t)(t * 32 + 2)) * 128);
        __syncthreads();   // barB: P + ssum + K(t+1) visible
        // (f) accumulate l over 8 j-slices, both halves
#pragma unroll
        for (int h = 0; h < 2; ++h) {
            float a0 = 0.f;
#pragma unroll
            for (int w = 0; w < 8; ++w) a0 += ssum[w][h][l31];
            ls[h] += a0;
        }
        // (g) PV: 16 j-steps of 16; own 32-c slice x both i-halves; rolling V prefetch
#pragma unroll
        for (int js = 0; js < 16; ++js) {
            f16x8 vv = (js & 1) ? vaB : vaA;
            if (js < 14) {
                f16x8 nv = *(const f16x8*)(vL + ((size_t)(t * 32 + (js + 2) * 2)) * 128);
                if (js & 1) vaB = nv; else vaA = nv;
            }
            f16x8 pb0 = *(const f16x8*)(&pbuf[l31 * 256 + (((js * 2 + lh) ^ sw) * 8)]);
            f16x8 pb1 = *(const f16x8*)(&pbuf[(32 + l31) * 256 + (((js * 2 + lh) ^ sw) * 8)]);
            __builtin_amdgcn_s_setprio(1);
            oacc[0] = __builtin_amdgcn_mfma_f32_32x32x16_f16(vv, pb0, oacc[0], 0, 0, 0);
            oacc[1] = __builtin_amdgcn_mfma_f32_32x32x16_f16(vv, pb1, oacc[1], 0, 0, 0);
            __builtin_amdgcn_s_setprio(0);
        }
        // pbuf reads of tile t finish before barA(t+1); writes of t+1 occur after it
    }

    // epilogue: O[c][i], 32 consecutive i per row (full 128B lines); + residual
    const float alpha = alphap[0];
#pragma unroll
    for (int h = 0; h < 2; ++h) {
        const float inv = alpha / ls[h];
        const int icol = i0 + h * 32 + l31;
#pragma unroll
        for (int r = 0; r < 16; ++r) {
            const int c = wv * 32 + (r & 3) + 8 * (r >> 2) + 4 * lh;
            const size_t off = (size_t)(b * C + c) * N + icol;
            out[off] = oacc[h][r] * inv + x[off];
        }
    }
}

extern "C" void kernel_launch(void* const* d_in, const int* in_sizes, int n_in,
                              void* d_out, int out_size, void* d_ws, size_t ws_size,
                              hipStream_t stream) {
    const float* x     = (const float*)d_in[0];
    const float* Wf_w  = (const float*)d_in[1];
    const float* Wf_b  = (const float*)d_in[2];
    const float* Wh_w  = (const float*)d_in[3];
    const float* Wh_b  = (const float*)d_in[4];
    const float* Wl_w  = (const float*)d_in[5];
    const float* Wl_b  = (const float*)d_in[6];
    const float* alpha = (const float*)d_in[7];
    char* ws = (char*)d_ws;
    f16*   xt   = (f16*)(ws + WS_XT);
    f16*   ftb  = (f16*)(ws + WS_FT);
    f16*   ktb  = (f16*)(ws + WS_KT);
    f16*   vb   = (f16*)(ws + WS_V);
    f16*   wcat = (f16*)(ws + WS_WCAT);
    f16*   wl   = (f16*)(ws + WS_WL);
    float* bcat = (float*)(ws + WS_BC);
    float* out  = (float*)d_out;

    prep_weights<<<dim3((C * C + 255) / 256), dim3(256), 0, stream>>>(Wf_w, Wf_b, Wh_w, Wh_b, Wl_w, wcat, wl, bcat);
    transpose_x<<<dim3(BATCH * 8 * 64), dim3(256), 0, stream>>>(x, xt);
    proj_fk<<<dim3(256), dim3(256), 0, stream>>>(xt, wcat, bcat, ftb, ktb);
    proj_v<<<dim3(512), dim3(256), 0, stream>>>(xt, wl, Wl_b, vb);
    // 4 b x 64 query-tiles(64q) = 256 blocks x 16 waves = 4 waves/SIMD, XCD-pinned
    attn<<<dim3(256), dim3(1024), 0, stream>>>(ftb, ktb, vb, x, alpha, out);
}

// Round 16
// 167.934 us; speedup vs baseline: 1.2803x; 1.2803x over previous
//
#include <hip/hip_runtime.h>
#include <hip/hip_bf16.h>

typedef _Float16 f16;
typedef _Float16 f16x4 __attribute__((ext_vector_type(4)));
typedef _Float16 f16x8 __attribute__((ext_vector_type(8)));
typedef float f32x4 __attribute__((ext_vector_type(4)));

constexpr int BATCH = 4, C = 512, CQ = 128, N = 4096;
constexpr int OALL = 768; // stacked outputs: f(128) + k(128) + v(512)

// workspace layout (bytes)
constexpr size_t WS_FT   = 0;                                      // f16 [B][N][128]       4 MB
constexpr size_t WS_KT   = WS_FT   + (size_t)BATCH * N * CQ * 2;   // f16 [B][N/4][4][128]  4 MB (tiled K)
constexpr size_t WS_V    = WS_KT   + (size_t)BATCH * N * CQ * 2;   // f16 [B][C/16][N/8][16][8] 16 MB (tiled V)
constexpr size_t WS_WALL = WS_V    + (size_t)BATCH * C * N * 2;    // f16 [768][512]
constexpr size_t WS_BALL = WS_WALL + (size_t)OALL * C * 2;         // f32 [768]

// ---------------------------------------------------------------- stacked weights->fp16
__global__ void prep_weights(const float* __restrict__ Wf_w, const float* __restrict__ Wf_b,
                             const float* __restrict__ Wh_w, const float* __restrict__ Wh_b,
                             const float* __restrict__ Wl_w, const float* __restrict__ Wl_b,
                             f16* __restrict__ wall, float* __restrict__ ball) {
    int i = blockIdx.x * 256 + threadIdx.x;                 // grid covers 768*512
    if (i < OALL * C) {
        int o = i >> 9, c = i & 511;
        float v = (o < 128) ? Wf_w[o * C + c]
                : (o < 256) ? Wh_w[(o - 128) * C + c]
                            : Wl_w[(o - 256) * C + c];
        wall[i] = (f16)v;
    }
    if (i < OALL)
        ball[i] = (i < 128) ? Wf_b[i] : (i < 256) ? Wh_b[i - 128] : Wl_b[i - 256];
}

// ---------------------------------------------------------------- fused projections (v16)
// One kernel replaces transpose_x + proj_fk + proj_v. Block = 512 thr (8 waves),
// one (b, 64n) tile. Per 64-c chunk: stage x[64c][64n] f32 -> LDS f16 transposed
// [64n][72c]; each wave computes its 96-o slice of stacked W (768x512, L2-res).
// Epilogue routes per o-frag (16-aligned boundaries): o<128 -> ft (n-major),
// o<256 -> kt tiled [b][n/4][4][128], else -> v tiled [b][cp][jb][16][8].
__global__ void __launch_bounds__(512) proj_all(const float* __restrict__ x, const f16* __restrict__ wall,
                                                const float* __restrict__ ball,
                                                f16* __restrict__ ft, f16* __restrict__ kt,
                                                f16* __restrict__ v) {
    __shared__ __align__(16) f16 xl[64][72];   // 9 KB, 72-pad for b128 alignment
    const int tid = threadIdx.x;
    const int wv  = tid >> 6;
    const int lane = tid & 63;
    const int li = lane & 15, lg = lane >> 4;
    const int b  = blockIdx.x >> 6;
    const int n0 = (blockIdx.x & 63) * 64;
    const int ob = wv * 96;                    // wave's output slice (6 frags of 16)
    const int nn = tid & 63, cg = tid >> 6;    // staging decode: 8 c-groups of 8

    f32x4 acc[6][4] = {};                      // [o-frag][n-frag]
    for (int ch = 0; ch < 8; ++ch) {
        __syncthreads();                       // xl free (readers of prev chunk done)
        {   // stage 64c x 64n f32 -> xl[n][c] f16 (global reads coalesced along n)
            const float* xs = x + ((size_t)(b * C) + ch * 64 + cg * 8) * N + n0 + nn;
#pragma unroll
            for (int r = 0; r < 8; ++r)
                xl[nn][cg * 8 + r] = (f16)xs[(size_t)r * N];
        }
        __syncthreads();
#pragma unroll
        for (int ks = 0; ks < 2; ++ks) {
            f16x8 xfr[4];
#pragma unroll
            for (int nf = 0; nf < 4; ++nf)
                xfr[nf] = *(const f16x8*)(&xl[nf * 16 + li][ks * 32 + lg * 8]);
#pragma unroll
            for (int of = 0; of < 6; ++of) {
                f16x8 wfr = *(const f16x8*)(wall + (size_t)(ob + of * 16 + li) * C + ch * 64 + ks * 32 + lg * 8);
#pragma unroll
                for (int nf = 0; nf < 4; ++nf)
                    acc[of][nf] = __builtin_amdgcn_mfma_f32_16x16x32_f16(xfr[nf], wfr, acc[of][nf], 0, 0, 0);
            }
        }
    }
    // epilogue: D col(li) = o (B-operand row), D row (lg*4+r) = n (A-operand row)
#pragma unroll
    for (int of = 0; of < 6; ++of) {
        const int o = ob + of * 16 + li;
        const float bias = ball[o];
#pragma unroll
        for (int nf = 0; nf < 4; ++nf)
#pragma unroll
            for (int r = 0; r < 4; ++r) {
                const int n = n0 + nf * 16 + lg * 4 + r;
                const f16 val = (f16)(acc[of][nf][r] + bias);
                if (o < 128) {
                    ft[(size_t)(b * N + n) * CQ + o] = val;
                } else if (o < 256) {
                    const int ck = o - 128;
                    kt[(((size_t)b * (N >> 2) + (n >> 2)) * 4 + (n & 3)) * 128 + ck] = val;
                } else {
                    const int c = o - 256;
                    v[(((size_t)b * 32 + (c >> 4)) * 512 + (n >> 3)) * 128 + (c & 15) * 8 + (n & 7)] = val;
                }
            }
    }
}

// ---------------------------------------------------------------- flash attention + residual (v12 champion, verbatim)
// 8 waves, 64q tile, KVBLK=128, reg-staged double-buffered kbuf, shared-stats
// softmax, 2 barriers/iter, rolling V prefetch, 256 blocks XCD-pinned.
// Tiled operands: kt staging 1KB contiguous/instr; V fragments 1KB contiguous.
__global__ void __launch_bounds__(512, 2) attn(const f16* __restrict__ ft, const f16* __restrict__ kt,
                                               const f16* __restrict__ v,
                                               const float* __restrict__ x, const float* __restrict__ alphap,
                                               float* __restrict__ out) {
    __shared__ __align__(16) f16 kbuf[2][128 * 128];   // 64 KB K tile, double-buffered
    __shared__ __align__(16) f16 pbuf[64 * 128];       // 16 KB shared P
    __shared__ float smax[8][4][16];
    __shared__ float ssum[8][4][16];

    const int tid  = threadIdx.x;
    const int wv   = tid >> 6;
    const int lane = tid & 63;
    const int li = lane & 15, lg = lane >> 4;
    const int swl = li & 7;
    // XCD-pinning: under blk%8 round-robin, each XCD sees a single batch
    const int v0 = blockIdx.x;
    const int b  = (v0 & 7) >> 1;
    const int it = ((v0 & 1) << 5) | (v0 >> 3);
    const int i0 = it * 64;
    const int c0 = wv * 64;

    // F fragments (B operand of swapped QK): col=i, k=ck; 4 i-frags
    f16x8 fb[4][4];
#pragma unroll
    for (int f = 0; f < 4; ++f) {
        const f16* fp = ft + (size_t)(b * N + i0 + f * 16 + li) * CQ + lg * 8;
#pragma unroll
        for (int ks = 0; ks < 4; ++ks) fb[f][ks] = *(const f16x8*)(fp + ks * 32);
    }

    // K staging from tiled kt: instr k covers rows wv*16 + k*4 + lg, granule li
    // (contiguous 1KB). LDS write applies XOR ^(row&7); QK reader uses swl.
    const f16* ktb = kt + (size_t)b * N * 128;
    {   // prologue: stage tile 0 -> kbuf[0]
#pragma unroll
        for (int k = 0; k < 4; ++k) {
            f16x8 vv = *(const f16x8*)(ktb + (((size_t)(wv * 4 + k)) * 4 + lg) * 128 + li * 8);
            *(f16x8*)(&kbuf[0][(wv * 16 + k * 4 + lg) * 128 + ((li ^ ((k * 4 + lg) & 7)) * 8)]) = vv;
        }
    }

    // tiled V base: fragment (cf, phase) at vb2 + (cf*512 + t*16 + ph*4)*128
    const f16* vb2 = v + (((size_t)b * 32 + wv * 4) * 512 + lg) * 128 + li * 8;
    f32x4 oacc[4][4] = {};                       // [c-frag][i-frag]
    float ms[4] = {-1e30f, -1e30f, -1e30f, -1e30f};
    float ls[4] = {0.f, 0.f, 0.f, 0.f};
    __syncthreads();

    for (int t = 0; t < 32; ++t) {
        const f16* kc = &kbuf[t & 1][0];
        f16*       kn = &kbuf[(t + 1) & 1][0];
        const size_t jb0 = (size_t)t * 16;
        // (a) issue next K-tile global loads early (T14 issue-early/write-late)
        const int gn = (t < 31) ? (t + 1) * 32 : 0;   // group base = tile*32
        f16x8 stg[4];
#pragma unroll
        for (int k = 0; k < 4; ++k)
            stg[k] = *(const f16x8*)(ktb + (((size_t)(gn + wv * 4 + k)) * 4 + lg) * 128 + li * 8);

        // (b) QK for this wave's 16-j slice, all 4 i-frags
        f16x8 kf4[4];
#pragma unroll
        for (int ks = 0; ks < 4; ++ks)
            kf4[ks] = *(const f16x8*)(&kc[(wv * 16 + li) * 128 + ((ks * 4 + lg) ^ swl) * 8]);
        f32x4 s[4] = {};
        __builtin_amdgcn_s_setprio(1);
#pragma unroll
        for (int ks = 0; ks < 4; ++ks)
#pragma unroll
            for (int f = 0; f < 4; ++f)
                s[f] = __builtin_amdgcn_mfma_f32_16x16x32_f16(kf4[ks], fb[f][ks], s[f], 0, 0, 0);
        __builtin_amdgcn_s_setprio(0);

        // (c) wave-local max per query (rows j = wv*16 + lg*4 + r)
        float tm[4];
#pragma unroll
        for (int f = 0; f < 4; ++f) {
            float t0 = fmaxf(fmaxf(s[f][0], s[f][1]), fmaxf(s[f][2], s[f][3]));
            t0 = fmaxf(t0, __shfl_xor(t0, 16));
            t0 = fmaxf(t0, __shfl_xor(t0, 32));
            tm[f] = t0;
        }
        if (lane < 16) {
#pragma unroll
            for (int f = 0; f < 4; ++f) smax[wv][f][li] = tm[f];
        }
        // V prefetch for PV kf=0, issued before the barrier (latency hides under it)
        f16x8 va[2][4];
#pragma unroll
        for (int cf = 0; cf < 4; ++cf) va[0][cf] = *(const f16x8*)(vb2 + ((size_t)cf * 512 + jb0) * 128);
        __syncthreads();   // B1: max stats visible
        // (d) tile max over 8 waves (broadcast reads)
        float gm[4];
#pragma unroll
        for (int f = 0; f < 4; ++f) {
            float m0 = smax[0][f][li];
#pragma unroll
            for (int w = 1; w < 8; ++w) m0 = fmaxf(m0, smax[w][f][li]);
            gm[f] = m0;
        }
        // V prefetch for kf=1
#pragma unroll
        for (int cf = 0; cf < 4; ++cf) va[1][cf] = *(const f16x8*)(vb2 + ((size_t)cf * 512 + jb0 + 4) * 128);
        // T13 deferred rescale (identical decision in all waves: shared stats)
#pragma unroll
        for (int f = 0; f < 4; ++f) {
            if (!__all(gm[f] <= ms[f] + 8.0f)) {
                float mn = fmaxf(ms[f], gm[f]), sc = __expf(ms[f] - mn);
                ms[f] = mn; ls[f] *= sc;
#pragma unroll
                for (int cf = 0; cf < 4; ++cf) oacc[cf][f] *= sc;
            }
        }
        // exp (this wave's 4 j per lane per f) + P write + partial sums
        const int jl = wv * 16 + lg * 4;
        const int gg = (jl >> 3) ^ swl;
        float ps[4];
#pragma unroll
        for (int f = 0; f < 4; ++f) {
            f16x4 pk;
            float p0 = 0.f;
#pragma unroll
            for (int r = 0; r < 4; ++r) { float p = __expf(s[f][r] - ms[f]); p0 += p; pk[r] = (f16)p; }
            *(f16x4*)(&pbuf[(f * 16 + li) * 128 + gg * 8 + (jl & 7)]) = pk;
            ps[f] = p0;
        }
#pragma unroll
        for (int f = 0; f < 4; ++f) {
            ps[f] += __shfl_xor(ps[f], 16);
            ps[f] += __shfl_xor(ps[f], 32);
        }
        if (lane < 16) {
#pragma unroll
            for (int f = 0; f < 4; ++f) ssum[wv][f][li] = ps[f];
        }
        // write staged K tile to next buffer (loads from (a) drained by now)
#pragma unroll
        for (int k = 0; k < 4; ++k)
            *(f16x8*)(&kn[(wv * 16 + k * 4 + lg) * 128 + ((li ^ ((k * 4 + lg) & 7)) * 8)]) = stg[k];
        __syncthreads();   // B2: P + ssum + next-K visible
        // (f) accumulate l from shared partial sums
#pragma unroll
        for (int f = 0; f < 4; ++f) {
            float a0 = 0.f;
#pragma unroll
            for (int w = 0; w < 8; ++w) a0 += ssum[w][f][li];
            ls[f] += a0;
        }
        // (g) PV over full 128 j, this wave's 64 channels; rolling V prefetch
#pragma unroll
        for (int kf = 0; kf < 4; ++kf) {
            const int cur = kf & 1;
            const int g = (kf * 4 + lg) ^ swl;
            f16x8 pb[4];
#pragma unroll
            for (int f = 0; f < 4; ++f)
                pb[f] = *(const f16x8*)(&pbuf[(f * 16 + li) * 128 + g * 8]);
            f16x8 vv0 = va[cur][0], vv1 = va[cur][1], vv2 = va[cur][2], vv3 = va[cur][3];
            if (kf < 2) {
#pragma unroll
                for (int cf = 0; cf < 4; ++cf)
                    va[cur][cf] = *(const f16x8*)(vb2 + ((size_t)cf * 512 + jb0 + (kf + 2) * 4) * 128);
            }
            __builtin_amdgcn_s_setprio(1);
#pragma unroll
            for (int f = 0; f < 4; ++f) {
                oacc[0][f] = __builtin_amdgcn_mfma_f32_16x16x32_f16(vv0, pb[f], oacc[0][f], 0, 0, 0);
                oacc[1][f] = __builtin_amdgcn_mfma_f32_16x16x32_f16(vv1, pb[f], oacc[1][f], 0, 0, 0);
                oacc[2][f] = __builtin_amdgcn_mfma_f32_16x16x32_f16(vv2, pb[f], oacc[2][f], 0, 0, 0);
                oacc[3][f] = __builtin_amdgcn_mfma_f32_16x16x32_f16(vv3, pb[f], oacc[3][f], 0, 0, 0);
            }
            __builtin_amdgcn_s_setprio(0);
        }
        // no 3rd barrier: next iter's B1 orders pbuf/kbuf reuse
    }

    // epilogue: O[c][i], i coalesced over li; + residual
    const float alpha = alphap[0];
#pragma unroll
    for (int f = 0; f < 4; ++f) {
        const float invf = alpha / ls[f];
        const float* xp = x + (size_t)(b * C + c0) * N + i0 + f * 16 + li;
        float* op = out + (size_t)(b * C + c0) * N + i0 + f * 16 + li;
#pragma unroll
        for (int cf = 0; cf < 4; ++cf)
#pragma unroll
            for (int r = 0; r < 4; ++r) {
                const int cl = cf * 16 + lg * 4 + r;
                op[(size_t)cl * N] = oacc[cf][f][r] * invf + xp[(size_t)cl * N];
            }
    }
}

extern "C" void kernel_launch(void* const* d_in, const int* in_sizes, int n_in,
                              void* d_out, int out_size, void* d_ws, size_t ws_size,
                              hipStream_t stream) {
    const float* x     = (const float*)d_in[0];
    const float* Wf_w  = (const float*)d_in[1];
    const float* Wf_b  = (const float*)d_in[2];
    const float* Wh_w  = (const float*)d_in[3];
    const float* Wh_b  = (const float*)d_in[4];
    const float* Wl_w  = (const float*)d_in[5];
    const float* Wl_b  = (const float*)d_in[6];
    const float* alpha = (const float*)d_in[7];
    char* ws = (char*)d_ws;
    f16*   ftb  = (f16*)(ws + WS_FT);
    f16*   ktb  = (f16*)(ws + WS_KT);
    f16*   vb   = (f16*)(ws + WS_V);
    f16*   wall = (f16*)(ws + WS_WALL);
    float* ball = (float*)(ws + WS_BALL);
    float* out  = (float*)d_out;

    prep_weights<<<dim3((OALL * C + 255) / 256), dim3(256), 0, stream>>>(Wf_w, Wf_b, Wh_w, Wh_b, Wl_w, Wl_b, wall, ball);
    // fused projections: 4 b x 64 n-tiles = 256 blocks x 8 waves
    proj_all<<<dim3(256), dim3(512), 0, stream>>>(x, wall, ball, ftb, ktb, vb);
    // 4 b x 64 query-tiles(64q) = 256 blocks x 8 waves = 1 block/CU, XCD-pinned
    attn<<<dim3(256), dim3(512), 0, stream>>>(ftb, ktb, vb, x, alpha, out);
}

// Round 17
// 160.474 us; speedup vs baseline: 1.3398x; 1.0465x over previous
//
#include <hip/hip_runtime.h>
#include <hip/hip_bf16.h>

typedef _Float16 f16;
typedef _Float16 f16x4 __attribute__((ext_vector_type(4)));
typedef _Float16 f16x8 __attribute__((ext_vector_type(8)));
typedef float f32x4 __attribute__((ext_vector_type(4)));

constexpr int BATCH = 4, C = 512, CQ = 128, N = 4096;
constexpr int OALL = 768; // stacked outputs: f(128) + k(128) + v(512)

// workspace layout (bytes)
constexpr size_t WS_FT   = 0;                                      // f16 [B][N][128]       4 MB
constexpr size_t WS_KT   = WS_FT   + (size_t)BATCH * N * CQ * 2;   // f16 [B][N][128]       4 MB (K, row-major)
constexpr size_t WS_V    = WS_KT   + (size_t)BATCH * N * CQ * 2;   // f16 [B][C/16][N/8][16][8] 16 MB (tiled V)
constexpr size_t WS_WALL = WS_V    + (size_t)BATCH * C * N * 2;    // f16 [768][512]
constexpr size_t WS_BALL = WS_WALL + (size_t)OALL * C * 2;         // f32 [768]

// ---------------------------------------------------------------- stacked weights->fp16
__global__ void prep_weights(const float* __restrict__ Wf_w, const float* __restrict__ Wf_b,
                             const float* __restrict__ Wh_w, const float* __restrict__ Wh_b,
                             const float* __restrict__ Wl_w, const float* __restrict__ Wl_b,
                             f16* __restrict__ wall, float* __restrict__ ball) {
    int i = blockIdx.x * 256 + threadIdx.x;                 // grid covers 768*512
    if (i < OALL * C) {
        int o = i >> 9, c = i & 511;
        float v = (o < 128) ? Wf_w[o * C + c]
                : (o < 256) ? Wh_w[(o - 128) * C + c]
                            : Wl_w[(o - 256) * C + c];
        wall[i] = (f16)v;
    }
    if (i < OALL)
        ball[i] = (i < 128) ? Wf_b[i] : (i < 256) ? Wh_b[i - 128] : Wl_b[i - 256];
}

// ---------------------------------------------------------------- fused projections (v16, unchanged)
// One kernel replaces transpose_x + proj_fk + proj_v. Block = 512 thr (8 waves),
// one (b, 64n) tile. Per 64-c chunk: stage x[64c][64n] f32 -> LDS f16 transposed
// [64n][72c]; each wave computes its 96-o slice of stacked W (768x512, L2-res).
__global__ void __launch_bounds__(512) proj_all(const float* __restrict__ x, const f16* __restrict__ wall,
                                                const float* __restrict__ ball,
                                                f16* __restrict__ ft, f16* __restrict__ kt,
                                                f16* __restrict__ v) {
    __shared__ __align__(16) f16 xl[64][72];   // 9 KB, 72-pad for b128 alignment
    const int tid = threadIdx.x;
    const int wv  = tid >> 6;
    const int lane = tid & 63;
    const int li = lane & 15, lg = lane >> 4;
    const int b  = blockIdx.x >> 6;
    const int n0 = (blockIdx.x & 63) * 64;
    const int ob = wv * 96;                    // wave's output slice (6 frags of 16)
    const int nn = tid & 63, cg = tid >> 6;    // staging decode: 8 c-groups of 8

    f32x4 acc[6][4] = {};                      // [o-frag][n-frag]
    for (int ch = 0; ch < 8; ++ch) {
        __syncthreads();                       // xl free (readers of prev chunk done)
        {   // stage 64c x 64n f32 -> xl[n][c] f16 (global reads coalesced along n)
            const float* xs = x + ((size_t)(b * C) + ch * 64 + cg * 8) * N + n0 + nn;
#pragma unroll
            for (int r = 0; r < 8; ++r)
                xl[nn][cg * 8 + r] = (f16)xs[(size_t)r * N];
        }
        __syncthreads();
#pragma unroll
        for (int ks = 0; ks < 2; ++ks) {
            f16x8 xfr[4];
#pragma unroll
            for (int nf = 0; nf < 4; ++nf)
                xfr[nf] = *(const f16x8*)(&xl[nf * 16 + li][ks * 32 + lg * 8]);
#pragma unroll
            for (int of = 0; of < 6; ++of) {
                f16x8 wfr = *(const f16x8*)(wall + (size_t)(ob + of * 16 + li) * C + ch * 64 + ks * 32 + lg * 8);
#pragma unroll
                for (int nf = 0; nf < 4; ++nf)
                    acc[of][nf] = __builtin_amdgcn_mfma_f32_16x16x32_f16(xfr[nf], wfr, acc[of][nf], 0, 0, 0);
            }
        }
    }
    // epilogue: D col(li) = o (B-operand row), D row (lg*4+r) = n (A-operand row)
#pragma unroll
    for (int of = 0; of < 6; ++of) {
        const int o = ob + of * 16 + li;
        const float bias = ball[o];
#pragma unroll
        for (int nf = 0; nf < 4; ++nf)
#pragma unroll
            for (int r = 0; r < 4; ++r) {
                const int n = n0 + nf * 16 + lg * 4 + r;
                const f16 val = (f16)(acc[of][nf][r] + bias);
                if (o < 128) {
                    ft[(size_t)(b * N + n) * CQ + o] = val;
                } else if (o < 256) {
                    const int ck = o - 128;
                    kt[((size_t)b * N + n) * 128 + ck] = val;
                } else {
                    const int c = o - 256;
                    v[(((size_t)b * 32 + (c >> 4)) * 512 + (n >> 3)) * 128 + (c & 15) * 8 + (n & 7)] = val;
                }
            }
    }
}

// ---------------------------------------------------------------- flash attention + residual (v17)
// = v12 champion schedule with the K LDS round-trip REMOVED: each wave's QK only
// ever reads the 16 K-rows it staged itself (no cross-wave K sharing), so K
// fragments now load DIRECTLY global->registers from row-major kt (L2-resident),
// double-buffered kf/kfn with a full iteration of latency cover and zero barrier
// coupling. LDS shrinks 86->21 KB; K-path bank conflicts and 8 LDS ops/iter gone.
// pbuf/smax/ssum structure and both barriers unchanged (same hazard proofs).
__global__ void __launch_bounds__(512, 2) attn(const f16* __restrict__ ft, const f16* __restrict__ kt,
                                               const f16* __restrict__ v,
                                               const float* __restrict__ x, const float* __restrict__ alphap,
                                               float* __restrict__ out) {
    __shared__ __align__(16) f16 pbuf[64 * 128];       // 16 KB shared P
    __shared__ float smax[8][4][16];
    __shared__ float ssum[8][4][16];

    const int tid  = threadIdx.x;
    const int wv   = tid >> 6;
    const int lane = tid & 63;
    const int li = lane & 15, lg = lane >> 4;
    const int swl = li & 7;
    // XCD-pinning: under blk%8 round-robin, each XCD sees a single batch
    const int v0 = blockIdx.x;
    const int b  = (v0 & 7) >> 1;
    const int it = ((v0 & 1) << 5) | (v0 >> 3);
    const int i0 = it * 64;
    const int c0 = wv * 64;

    // F fragments (B operand of swapped QK): col=i, k=ck; 4 i-frags
    f16x8 fb[4][4];
#pragma unroll
    for (int f = 0; f < 4; ++f) {
        const f16* fp = ft + (size_t)(b * N + i0 + f * 16 + li) * CQ + lg * 8;
#pragma unroll
        for (int ks = 0; ks < 4; ++ks) fb[f][ks] = *(const f16x8*)(fp + ks * 32);
    }

    // direct-register K: lane reads row (t*128 + wv*16 + li), cols ks*32 + lg*8
    const f16* kL = kt + ((size_t)b * N + wv * 16 + li) * 128 + lg * 8;
    f16x8 kf[4];
#pragma unroll
    for (int ks = 0; ks < 4; ++ks) kf[ks] = *(const f16x8*)(kL + ks * 32);

    // tiled V base: fragment (cf, phase) at vb2 + (cf*512 + t*16 + ph*4)*128
    const f16* vb2 = v + (((size_t)b * 32 + wv * 4) * 512 + lg) * 128 + li * 8;
    f32x4 oacc[4][4] = {};                       // [c-frag][i-frag]
    float ms[4] = {-1e30f, -1e30f, -1e30f, -1e30f};
    float ls[4] = {0.f, 0.f, 0.f, 0.f};

    for (int t = 0; t < 32; ++t) {
        const size_t jb0 = (size_t)t * 16;
        // (a) prefetch next K tile fragments into kfn (whole iteration of cover)
        f16x8 kfn[4];
        const size_t knext = (size_t)((t < 31) ? (t + 1) : 0) * 128 * 128;
#pragma unroll
        for (int ks = 0; ks < 4; ++ks) kfn[ks] = *(const f16x8*)(kL + knext + ks * 32);

        // (b) QK for this wave's 16-j slice, all 4 i-frags (K from registers)
        f32x4 s[4] = {};
        __builtin_amdgcn_s_setprio(1);
#pragma unroll
        for (int ks = 0; ks < 4; ++ks)
#pragma unroll
            for (int f = 0; f < 4; ++f)
                s[f] = __builtin_amdgcn_mfma_f32_16x16x32_f16(kf[ks], fb[f][ks], s[f], 0, 0, 0);
        __builtin_amdgcn_s_setprio(0);

        // (c) wave-local max per query (rows j = wv*16 + lg*4 + r)
        float tm[4];
#pragma unroll
        for (int f = 0; f < 4; ++f) {
            float t0 = fmaxf(fmaxf(s[f][0], s[f][1]), fmaxf(s[f][2], s[f][3]));
            t0 = fmaxf(t0, __shfl_xor(t0, 16));
            t0 = fmaxf(t0, __shfl_xor(t0, 32));
            tm[f] = t0;
        }
        if (lane < 16) {
#pragma unroll
            for (int f = 0; f < 4; ++f) smax[wv][f][li] = tm[f];
        }
        // V prefetch for PV kf=0, issued before the barrier (latency hides under it)
        f16x8 va[2][4];
#pragma unroll
        for (int cf = 0; cf < 4; ++cf) va[0][cf] = *(const f16x8*)(vb2 + ((size_t)cf * 512 + jb0) * 128);
        __syncthreads();   // B1: max stats visible
        // (d) tile max over 8 waves (broadcast reads)
        float gm[4];
#pragma unroll
        for (int f = 0; f < 4; ++f) {
            float m0 = smax[0][f][li];
#pragma unroll
            for (int w = 1; w < 8; ++w) m0 = fmaxf(m0, smax[w][f][li]);
            gm[f] = m0;
        }
        // V prefetch for kf=1
#pragma unroll
        for (int cf = 0; cf < 4; ++cf) va[1][cf] = *(const f16x8*)(vb2 + ((size_t)cf * 512 + jb0 + 4) * 128);
        // T13 deferred rescale (identical decision in all waves: shared stats)
#pragma unroll
        for (int f = 0; f < 4; ++f) {
            if (!__all(gm[f] <= ms[f] + 8.0f)) {
                float mn = fmaxf(ms[f], gm[f]), sc = __expf(ms[f] - mn);
                ms[f] = mn; ls[f] *= sc;
#pragma unroll
                for (int cf = 0; cf < 4; ++cf) oacc[cf][f] *= sc;
            }
        }
        // exp (this wave's 4 j per lane per f) + P write + partial sums
        const int jl = wv * 16 + lg * 4;
        const int gg = (jl >> 3) ^ swl;
        float ps[4];
#pragma unroll
        for (int f = 0; f < 4; ++f) {
            f16x4 pk;
            float p0 = 0.f;
#pragma unroll
            for (int r = 0; r < 4; ++r) { float p = __expf(s[f][r] - ms[f]); p0 += p; pk[r] = (f16)p; }
            *(f16x4*)(&pbuf[(f * 16 + li) * 128 + gg * 8 + (jl & 7)]) = pk;
            ps[f] = p0;
        }
#pragma unroll
        for (int f = 0; f < 4; ++f) {
            ps[f] += __shfl_xor(ps[f], 16);
            ps[f] += __shfl_xor(ps[f], 32);
        }
        if (lane < 16) {
#pragma unroll
            for (int f = 0; f < 4; ++f) ssum[wv][f][li] = ps[f];
        }
        __syncthreads();   // B2: P + ssum visible
        // (f) accumulate l from shared partial sums
#pragma unroll
        for (int f = 0; f < 4; ++f) {
            float a0 = 0.f;
#pragma unroll
            for (int w = 0; w < 8; ++w) a0 += ssum[w][f][li];
            ls[f] += a0;
        }
        // (g) PV over full 128 j, this wave's 64 channels; rolling V prefetch
#pragma unroll
        for (int kf2 = 0; kf2 < 4; ++kf2) {
            const int cur = kf2 & 1;
            const int g = (kf2 * 4 + lg) ^ swl;
            f16x8 pb[4];
#pragma unroll
            for (int f = 0; f < 4; ++f)
                pb[f] = *(const f16x8*)(&pbuf[(f * 16 + li) * 128 + g * 8]);
            f16x8 vv0 = va[cur][0], vv1 = va[cur][1], vv2 = va[cur][2], vv3 = va[cur][3];
            if (kf2 < 2) {
#pragma unroll
                for (int cf = 0; cf < 4; ++cf)
                    va[cur][cf] = *(const f16x8*)(vb2 + ((size_t)cf * 512 + jb0 + (kf2 + 2) * 4) * 128);
            }
            __builtin_amdgcn_s_setprio(1);
#pragma unroll
            for (int f = 0; f < 4; ++f) {
                oacc[0][f] = __builtin_amdgcn_mfma_f32_16x16x32_f16(vv0, pb[f], oacc[0][f], 0, 0, 0);
                oacc[1][f] = __builtin_amdgcn_mfma_f32_16x16x32_f16(vv1, pb[f], oacc[1][f], 0, 0, 0);
                oacc[2][f] = __builtin_amdgcn_mfma_f32_16x16x32_f16(vv2, pb[f], oacc[2][f], 0, 0, 0);
                oacc[3][f] = __builtin_amdgcn_mfma_f32_16x16x32_f16(vv3, pb[f], oacc[3][f], 0, 0, 0);
            }
            __builtin_amdgcn_s_setprio(0);
        }
        // roll K double-buffer
#pragma unroll
        for (int ks = 0; ks < 4; ++ks) kf[ks] = kfn[ks];
        // no 3rd barrier: next iter's B1 orders pbuf reuse (same proof as v12)
    }

    // epilogue: O[c][i], i coalesced over li; + residual
    const float alpha = alphap[0];
#pragma unroll
    for (int f = 0; f < 4; ++f) {
        const float invf = alpha / ls[f];
        const float* xp = x + (size_t)(b * C + c0) * N + i0 + f * 16 + li;
        float* op = out + (size_t)(b * C + c0) * N + i0 + f * 16 + li;
#pragma unroll
        for (int cf = 0; cf < 4; ++cf)
#pragma unroll
            for (int r = 0; r < 4; ++r) {
                const int cl = cf * 16 + lg * 4 + r;
                op[(size_t)cl * N] = oacc[cf][f][r] * invf + xp[(size_t)cl * N];
            }
    }
}

extern "C" void kernel_launch(void* const* d_in, const int* in_sizes, int n_in,
                              void* d_out, int out_size, void* d_ws, size_t ws_size,
                              hipStream_t stream) {
    const float* x     = (const float*)d_in[0];
    const float* Wf_w  = (const float*)d_in[1];
    const float* Wf_b  = (const float*)d_in[2];
    const float* Wh_w  = (const float*)d_in[3];
    const float* Wh_b  = (const float*)d_in[4];
    const float* Wl_w  = (const float*)d_in[5];
    const float* Wl_b  = (const float*)d_in[6];
    const float* alpha = (const float*)d_in[7];
    char* ws = (char*)d_ws;
    f16*   ftb  = (f16*)(ws + WS_FT);
    f16*   ktb  = (f16*)(ws + WS_KT);
    f16*   vb   = (f16*)(ws + WS_V);
    f16*   wall = (f16*)(ws + WS_WALL);
    float* ball = (float*)(ws + WS_BALL);
    float* out  = (float*)d_out;

    prep_weights<<<dim3((OALL * C + 255) / 256), dim3(256), 0, stream>>>(Wf_w, Wf_b, Wh_w, Wh_b, Wl_w, Wl_b, wall, ball);
    // fused projections: 4 b x 64 n-tiles = 256 blocks x 8 waves
    proj_all<<<dim3(256), dim3(512), 0, stream>>>(x, wall, ball, ftb, ktb, vb);
    // 4 b x 64 query-tiles(64q) = 256 blocks x 8 waves = 1 block/CU, XCD-pinned
    attn<<<dim3(256), dim3(512), 0, stream>>>(ftb, ktb, vb, x, alpha, out);
}